// Round 8
// baseline (96.766 us; speedup 1.0000x reference)
//
#include <hip/hip_runtime.h>
#include <stdint.h>

#define NPTS 512
#define NB 4
#define TJB 128
#define BST 72     // bS row stride (halfs): 144 B, 16B-aligned; b128 read patterns <=2-way
#define SOST 40    // sO row stride (halfs): 80 B, 16B-aligned half8 reads, <=2-way writes

typedef __attribute__((ext_vector_type(4))) float floatx4;
typedef __fp16 fp16x2 __attribute__((ext_vector_type(2)));      // cvt_pkrtz return type
typedef _Float16 half2v __attribute__((ext_vector_type(2)));
typedef _Float16 half8v __attribute__((ext_vector_type(8)));

union H8 { fp16x2 p2[4]; half2v h2[4]; half8v h8; };

// ---------------- Kernel 1: per-row embedding chain, k-split ----------------
// One block (4 waves) per row; lane t owns channel t; each 64-K GEMV stage is
// split 16 k's per wave (chain depth 16), partials combined via LDS.
// 2048 blocks -> 8 blocks/CU -> full 32 waves/CU occupancy.
__global__ __launch_bounds__(256) void rows_kernel(
    const float* __restrict__ x,
    const float* __restrict__ Wf,  const float* __restrict__ bf,
    const float* __restrict__ Wp1, const float* __restrict__ bp1,
    const float* __restrict__ Wp2, const float* __restrict__ bp2,
    const float* __restrict__ Wn,  const float* __restrict__ bn,
    const float* __restrict__ W1,  const float* __restrict__ b1,
    _Float16* __restrict__ wsA, _Float16* __restrict__ wsB)
{
    __shared__ float poshS[64];
    __shared__ float projS[64];
    __shared__ float embS[64];
    __shared__ float partA[4][64];
    __shared__ float partB[4][64];

    const int t   = threadIdx.x & 63;
    const int w   = threadIdx.x >> 6;
    const int k0  = w * 16;
    const int row = blockIdx.x;
    const float* xr = x + row * 16;

    // stage 1: posh = relu(xyz @ Wp1 + bp1)  (wave 0 only; 3 FMAs)
    if (w == 0) {
        const float x13 = xr[13], x14 = xr[14], x15 = xr[15];
        float ph = x13 * Wp1[t] + x14 * Wp1[64 + t] + x15 * Wp1[128 + t] + bp1[t];
        poshS[t] = fmaxf(ph, 0.f);
    }
    __syncthreads();

    // stage 2: proj partials: Wp2 over k0..k0+15, feats over 4 k's, biases in w3
    {
        float s0 = 0.f, s1 = 0.f;
        #pragma unroll
        for (int k = 0; k < 16; k += 2) {
            s0 += poshS[k0 + k    ] * Wp2[(k0 + k    ) * 64 + t];
            s1 += poshS[k0 + k + 1] * Wp2[(k0 + k + 1) * 64 + t];
        }
        float p = s0 + s1;
        if (w < 3) {
            #pragma unroll
            for (int k = 0; k < 4; ++k) p += xr[w * 4 + k] * Wf[(w * 4 + k) * 64 + t];
        } else {
            p += xr[12] * Wf[12 * 64 + t] + bf[t] + bp2[t];
        }
        partA[w][t] = p;
    }
    __syncthreads();

    // combine -> projS
    if (w == 0) projS[t] = (partA[0][t] + partA[1][t]) + (partA[2][t] + partA[3][t]);
    __syncthreads();

    // stage 3: emb partials over Wn
    {
        float s0 = 0.f, s1 = 0.f;
        #pragma unroll
        for (int k = 0; k < 16; k += 2) {
            s0 += projS[k0 + k    ] * Wn[(k0 + k    ) * 64 + t];
            s1 += projS[k0 + k + 1] * Wn[(k0 + k + 1) * 64 + t];
        }
        partB[w][t] = s0 + s1 + ((w == 0) ? bn[t] : 0.f);
    }
    __syncthreads();

    if (w == 0) embS[t] = (partB[0][t] + partB[1][t]) + (partB[2][t] + partB[3][t]);
    __syncthreads();

    // stage 4: a/b partials over W1 (a gets b1 in wave 0)
    {
        float sa0 = 0.f, sa1 = 0.f, sb0 = 0.f, sb1 = 0.f;
        #pragma unroll
        for (int k = 0; k < 16; k += 2) {
            const float g0 = embS[k0 + k], g1 = embS[k0 + k + 1];
            sa0 += g0 * W1[(k0 + k    ) * 64 + t];
            sa1 += g1 * W1[(k0 + k + 1) * 64 + t];
            sb0 += g0 * W1[(64 + k0 + k    ) * 64 + t];
            sb1 += g1 * W1[(64 + k0 + k + 1) * 64 + t];
        }
        partA[w][t] = sa0 + sa1 + ((w == 0) ? b1[t] : 0.f);
        partB[w][t] = sb0 + sb1;
    }
    __syncthreads();

    if (w == 0)
        wsA[row * 64 + t] = (_Float16)((partA[0][t] + partA[1][t]) + (partA[2][t] + partA[3][t]));
    else if (w == 1)
        wsB[row * 64 + t] = (_Float16)((partB[0][t] + partB[1][t]) + (partB[2][t] + partB[3][t]));
}

// ---------------- Kernel 2: pairwise MLP, packed-f16 MFMA, 2 i/wave ----------------
__global__ __launch_bounds__(256) void pairs_kernel(
    const _Float16* __restrict__ wsA, const _Float16* __restrict__ wsB,
    const float* __restrict__ W2,  const float* __restrict__ b2,
    const float* __restrict__ W3,  const float* __restrict__ b3,
    float* __restrict__ out)
{
    __shared__ _Float16 bS[TJB][BST];
    __shared__ _Float16 sO[4][2][16][SOST];   // [wave][i-slot][j][sigma-m]

    const int tid = threadIdx.x;
    const int w   = tid >> 6;
    const int l   = tid & 63;
    const int q   = l >> 4;
    const int c   = l & 15;
    const int q8  = q * 8;

    const int bidx = blockIdx.x;
    const int jt = bidx & 3;             // 4 j-tiles of 128
    const int ig = (bidx >> 2) & 63;     // 64 i-groups of 8
    const int bb = bidx >> 8;            // batch
    const int j0 = jt * TJB;
    const int i0 = ig * 8 + w * 2;       // wave handles i0, i0+1

    // stage b-tile: 128 rows x 64 halfs = 16 KB
    const _Float16* bG = wsB + (bb * NPTS + j0) * 64;
    #pragma unroll
    for (int p = 0; p < 4; ++p) {
        const int flat = p * 256 + tid;
        const int rr = flat >> 3, ch = (flat & 7) * 8;
        *(half8v*)&bS[rr][ch] = *(const half8v*)(bG + rr * 64 + ch);
    }

    // W2 f16 fragments, B-layout: lane holds W2[k=kt*32+q8+e][nt*16+c]
    half8v Wf16[2][2];
    #pragma unroll
    for (int kt = 0; kt < 2; ++kt)
        #pragma unroll
        for (int nt = 0; nt < 2; ++nt) {
            H8 u;
            #pragma unroll
            for (int e = 0; e < 8; ++e)
                u.h8[e] = (_Float16)W2[(kt * 32 + q8 + e) * 32 + nt * 16 + c];
            Wf16[kt][nt] = u.h8;
        }

    // W3 sigma-permuted B-frag: pos p holds W3[(p>>1)+16*(p&1)]
    half8v w3f;
    #pragma unroll
    for (int e = 0; e < 8; ++e) {
        const int p = q8 + e;
        w3f[e] = (_Float16)W3[(p >> 1) + ((p & 1) << 4)];
    }

    const float b2c = b2[c], b2c16 = b2[c + 16];
    const float b3v = b3[0];

    // a-rows for both i (b1 folded), f16
    const _Float16* aG0 = wsA + (bb * NPTS + i0) * 64;
    const _Float16* aG1 = aG0 + 64;
    const half8v aA0 = *(const half8v*)(aG0 + q8);
    const half8v aA1 = *(const half8v*)(aG0 + 32 + q8);
    const half8v aB0 = *(const half8v*)(aG1 + q8);
    const half8v aB1 = *(const half8v*)(aG1 + 32 + q8);
    const half8v zero8 = (half8v)(_Float16)0.0f;

    __syncthreads();

    float* orow0 = out + ((size_t)(bb * NPTS + i0)) * NPTS + j0;
    float* orow1 = orow0 + NPTS;

    #pragma unroll 4
    for (int mt = 0; mt < 8; ++mt) {
        const int m = mt * 16 + c;
        const half8v b0v = *(const half8v*)&bS[m][q8];
        const half8v b1v = *(const half8v*)&bS[m][32 + q8];

        // H = relu(a + b), packed f16; b-rows shared across both i
        const half8v hA0 = __builtin_elementwise_max(aA0 + b0v, zero8);
        const half8v hA1 = __builtin_elementwise_max(aA1 + b1v, zero8);
        const half8v hB0 = __builtin_elementwise_max(aB0 + b0v, zero8);
        const half8v hB1 = __builtin_elementwise_max(aB1 + b1v, zero8);

        floatx4 aA0c = {b2c, b2c, b2c, b2c};
        floatx4 aA1c = {b2c16, b2c16, b2c16, b2c16};
        floatx4 aB0c = aA0c, aB1c = aA1c;
        aA0c = __builtin_amdgcn_mfma_f32_16x16x32_f16(hA0, Wf16[0][0], aA0c, 0, 0, 0);
        aA0c = __builtin_amdgcn_mfma_f32_16x16x32_f16(hA1, Wf16[1][0], aA0c, 0, 0, 0);
        aA1c = __builtin_amdgcn_mfma_f32_16x16x32_f16(hA0, Wf16[0][1], aA1c, 0, 0, 0);
        aA1c = __builtin_amdgcn_mfma_f32_16x16x32_f16(hA1, Wf16[1][1], aA1c, 0, 0, 0);
        aB0c = __builtin_amdgcn_mfma_f32_16x16x32_f16(hB0, Wf16[0][0], aB0c, 0, 0, 0);
        aB0c = __builtin_amdgcn_mfma_f32_16x16x32_f16(hB1, Wf16[1][0], aB0c, 0, 0, 0);
        aB1c = __builtin_amdgcn_mfma_f32_16x16x32_f16(hB0, Wf16[0][1], aB1c, 0, 0, 0);
        aB1c = __builtin_amdgcn_mfma_f32_16x16x32_f16(hB1, Wf16[1][1], aB1c, 0, 0, 0);

        // epilogue, both i: R = relu(S) -> sigma position 2c -> LDS -> MFMA vs W3
        #pragma unroll
        for (int r = 0; r < 4; ++r) {
            H8 pkA, pkB;
            pkA.p2[0] = __builtin_amdgcn_cvt_pkrtz(aA0c[r], aA1c[r]);
            pkA.h2[0] = __builtin_elementwise_max(pkA.h2[0], (half2v)(_Float16)0.0f);
            *(half2v*)&sO[w][0][q * 4 + r][2 * c] = pkA.h2[0];
            pkB.p2[0] = __builtin_amdgcn_cvt_pkrtz(aB0c[r], aB1c[r]);
            pkB.h2[0] = __builtin_elementwise_max(pkB.h2[0], (half2v)(_Float16)0.0f);
            *(half2v*)&sO[w][1][q * 4 + r][2 * c] = pkB.h2[0];
        }
        const half8v arA = *(const half8v*)&sO[w][0][c][q8];
        const half8v arB = *(const half8v*)&sO[w][1][c][q8];

        floatx4 dlA = {b3v, b3v, b3v, b3v};
        floatx4 dlB = {b3v, b3v, b3v, b3v};
        dlA = __builtin_amdgcn_mfma_f32_16x16x32_f16(arA, w3f, dlA, 0, 0, 0);
        dlB = __builtin_amdgcn_mfma_f32_16x16x32_f16(arB, w3f, dlB, 0, 0, 0);

        const float lgA = (c == 0) ? dlA[0] : ((c == 1) ? dlA[1] : ((c == 2) ? dlA[2] : dlA[3]));
        const float lgB = (c == 0) ? dlB[0] : ((c == 1) ? dlB[1] : ((c == 2) ? dlB[2] : dlB[3]));
        if (c < 4) {
            orow0[mt * 16 + q * 4 + c] = lgA;
            orow1[mt * 16 + q * 4 + c] = lgB;
        }
    }
}

extern "C" void kernel_launch(void* const* d_in, const int* in_sizes, int n_in,
                              void* d_out, int out_size, void* d_ws, size_t ws_size,
                              hipStream_t stream) {
    const float* x   = (const float*)d_in[0];
    const float* Wf  = (const float*)d_in[1];
    const float* bf  = (const float*)d_in[2];
    const float* Wp1 = (const float*)d_in[3];
    const float* bp1 = (const float*)d_in[4];
    const float* Wp2 = (const float*)d_in[5];
    const float* bp2 = (const float*)d_in[6];
    const float* Wn  = (const float*)d_in[7];
    const float* bn  = (const float*)d_in[8];
    const float* W1  = (const float*)d_in[9];
    const float* b1  = (const float*)d_in[10];
    const float* W2  = (const float*)d_in[11];
    const float* b2  = (const float*)d_in[12];
    const float* W3  = (const float*)d_in[13];
    const float* b3  = (const float*)d_in[14];

    _Float16* wsA = (_Float16*)d_ws;           // 2048*64 halfs (256 KB)
    _Float16* wsB = wsA + NB * NPTS * 64;      // 2048*64 halfs

    rows_kernel<<<NB * NPTS, 256, 0, stream>>>(
        x, Wf, bf, Wp1, bp1, Wp2, bp2, Wn, bn, W1, b1, wsA, wsB);

    pairs_kernel<<<NB * 64 * 4, 256, 0, stream>>>(
        wsA, wsB, W2, b2, W3, b3, (float*)d_out);
}